// Round 10
// baseline (593.702 us; speedup 1.0000x reference)
//
#include <hip/hip_runtime.h>
#include <math.h>

#define N    257     // state dim
#define AP   258     // doubles per A row (cols 0..256 = S, col 257 = rhs)
#define MM   128     // rotation pairs
#define LL   512     // seq length
#define BB   4       // batch
#define NB   32      // panel width (NB=64 spills: 512-thr blocks cap at 128 VGPR)
#define U12S 226     // U12 row stride (max strip width)

// ws byte layout (Pw/U12 double-buffered by panel parity):
#define A_BYTE    0         // double[257*258] = 530448
#define W0_BYTE   530448    // float[257]  -> 531476
#define CXY_BYTE  531488    // float[4096] -> 547872
#define PW_BYTE   547904    // 2 x double[32*257] = 2x65792 -> 679488
#define PWSZ      65792
#define U12_BYTE  679488    // 2 x double[32*226] = 2x57856 -> 795200
#define U12SZ     57856
#define ST_BYTE   795200    // float[257*257] = 264196 -> 1059396
// total ~1.06 MB (ws >= 1.31 MB)

// ---------------------------------------------------------------------------
// stage + scan in ONE dispatch: blocks 0..129 stage A=[S|z0] fp64 + St=S^T;
// block 130 does the prefix-sum scan (verified round-8/9 body).
// ---------------------------------------------------------------------------
__global__ __launch_bounds__(512) void stage_scan_kernel(const float* __restrict__ S,
                                                         const float* __restrict__ z0,
                                                         const float* __restrict__ x,
                                                         void* __restrict__ wsv) {
  const int tid = threadIdx.x;
  const int bid = blockIdx.x;

  if (bid < 130) {
    double* A  = (double*)((char*)wsv + A_BYTE);
    float*  St = (float*)((char*)wsv + ST_BYTE);
    const int idx = bid * 512 + tid;
    if (idx < N * N) {
      const int i = idx / N, j = idx - i * N;
      A[(size_t)i * AP + j] = (double)S[idx];
      St[idx] = S[j * N + i];          // St[d][i] = S[i][d]
    } else if (idx < N * N + N) {
      const int r = idx - N * N;
      A[(size_t)r * AP + N] = (double)z0[r];
    }
    return;
  }

  const int wave = tid >> 6, lane = tid & 63;
  const int b    = wave >> 1, comp = wave & 1;
  const float* xp = x + ((size_t)b * LL) * 2 + comp;
  double loc[8];
  double run = 0.0;
  #pragma unroll
  for (int e = 0; e < 8; ++e) {
    run += (double)xp[(lane * 8 + e) * 2];
    loc[e] = run;
  }
  double tot = run;
  #pragma unroll
  for (int off = 1; off < 64; off <<= 1) {
    const double o = __shfl_up(tot, off);
    if (lane >= off) tot += o;
  }
  const double excl = tot - run;
  float* cp = (float*)((char*)wsv + CXY_BYTE) + ((size_t)b * LL) * 2 + comp;
  #pragma unroll
  for (int e = 0; e < 8; ++e)
    cp[(lane * 8 + e) * 2] = (float)(excl + loc[e]);
}

// ---------------------------------------------------------------------------
// first panel factor (k0 = 0): round-6 verified register-resident Jordan.
// Writes Pw/U12 slot 0.
// ---------------------------------------------------------------------------
__global__ __launch_bounds__(512, 1) void panel_factor_kernel(void* __restrict__ wsv) {
  __shared__ double piv[2][NB];
  __shared__ double pinvs[2];
  __shared__ double F11s[NB][NB + 1];
  double* A    = (double*)((char*)wsv + A_BYTE);
  double* Pw   = (double*)((char*)wsv + PW_BYTE);      // slot 0
  double* U12w = (double*)((char*)wsv + U12_BYTE);     // slot 0
  const int tid = threadIdx.x;
  const int tc2 = 258 - NB;

  double r[NB];
  if (tid < N) {
    const double* Ar = A + (size_t)tid * AP;
    #pragma unroll
    for (int c = 0; c < NB; c += 2) {
      const double2 v = *(const double2*)&Ar[c];
      r[c] = v.x; r[c + 1] = v.y;
    }
  }
  if (tid == 0) {
    #pragma unroll
    for (int c = 0; c < NB; ++c) piv[0][c] = r[c];
    pinvs[0] = 1.0 / r[0];
  }
  __syncthreads();

  #pragma unroll
  for (int j = 0; j < NB; ++j) {
    const int bsel = j & 1;
    if (tid < N && tid > j) {
      const double f = r[j] * pinvs[bsel];
      #pragma unroll
      for (int j2 = j + 1; j2 < NB; ++j2)
        r[j2] -= f * piv[bsel][j2];
      r[j] = f;
      if (j + 1 < NB && tid == j + 1) {
        #pragma unroll
        for (int c = 0; c < NB; ++c)
          if (c > j) piv[bsel ^ 1][c] = r[c];
        pinvs[bsel ^ 1] = 1.0 / r[j + 1];
      }
    }
    __syncthreads();
  }

  if (tid < N) {
    if (tid < NB) {
      #pragma unroll
      for (int c = 0; c < NB; ++c) {
        F11s[tid][c] = r[c];
        A[(size_t)tid * AP + c] = r[c];
      }
    } else {
      #pragma unroll
      for (int t = 0; t < NB; ++t)
        Pw[(size_t)t * N + tid] = r[t];
    }
  }
  __syncthreads();

  if (tid < tc2) {
    double u[NB];
    #pragma unroll
    for (int jr = 0; jr < NB; ++jr)
      u[jr] = A[(size_t)jr * AP + NB + tid];
    #pragma unroll
    for (int jr = 1; jr < NB; ++jr) {
      double vv = u[jr];
      #pragma unroll
      for (int t = 0; t < jr; ++t)
        vv -= F11s[jr][t] * u[t];
      u[jr] = vv;
    }
    #pragma unroll
    for (int jr = 0; jr < NB; ++jr) {
      U12w[jr * U12S + tid] = u[jr];
      A[(size_t)jr * AP + NB + tid] = u[jr];
    }
  }
}

// ---------------------------------------------------------------------------
// LOOK-AHEAD fused dispatch p (p = 0..6) — round-9 structure (passed refcheck)
// with the round-10 LDS-pipe fix:
//   block 0   : factor(p+1), update(p) correction folded. Round-9 staged the
//               shared correction operands (U12 strip cols / band-p+1 Pw rows)
//               in LDS -> 2048 broadcast ds_reads per wave x 8 waves on ONE
//               CU's LDS pipe ~= 41us stall (54us dispatch). The operands are
//               WAVE-UNIFORM -> now read directly from global with uniform
//               addresses (compiler scalarizes to s_load / SMEM or uniform
//               VMEM; either way LDS pipe untouched).
//   blocks 1+ : update(p) on rows [0,k0u) U [ctf,N), cols [ctf,258).
// Pw/U12: read slot p&1, write slot (p+1)&1.
// ---------------------------------------------------------------------------
__global__ __launch_bounds__(512, 1) void update_factor_kernel(void* __restrict__ wsv,
                                                               int p) {
  __shared__ double piv[2][NB];
  __shared__ double pinvs[2];
  __shared__ double F11s[NB][NB + 1];
  __shared__ double Pl[NB][NB + 1];      // update: P tile
  __shared__ __align__(16) double Ul[NB][66];   // update: U12 tile

  double* A = (double*)((char*)wsv + A_BYTE);
  const int sl  = p & 1;
  const double* PwR  = (const double*)((const char*)wsv + PW_BYTE  + sl * PWSZ);
  const double* U12R = (const double*)((const char*)wsv + U12_BYTE + sl * U12SZ);
  double* PwW  = (double*)((char*)wsv + PW_BYTE  + (sl ^ 1) * PWSZ);
  double* U12W = (double*)((char*)wsv + U12_BYTE + (sl ^ 1) * U12SZ);

  const int tid = threadIdx.x;
  const int bid = blockIdx.x;
  const int k0u = p * NB;          // panel p base
  const int k0f = k0u + NB;        // panel p+1 base (= factor k0)
  const int ctf = k0f + NB;        // trailing base after panel p+1
  const int tc2 = 258 - ctf;       // trailing width (factor U12 AND update cols)

  if (bid == 0) {
    // ---------- factor(p+1) with folded correction ----------
    // stage panel cols [k0f, ctf)
    double r[NB];
    if (tid < N) {
      const double* Ar = A + (size_t)tid * AP + k0f;
      #pragma unroll
      for (int c = 0; c < NB; c += 2) {
        const double2 v = *(const double2*)&Ar[c];
        r[c] = v.x; r[c + 1] = v.y;
      }
    }
    // apply update(p) correction; band-p rows frozen via pw=0 (branchless,
    // uniform flow so the U12R reads scalarize). U12R[t*U12S+c] is uniform.
    {
      const int  rc     = (tid < N) ? tid : 0;
      const bool frozen = (tid >= k0u && tid < k0f) || tid >= N;
      #pragma unroll 2
      for (int t = 0; t < NB; ++t) {
        const double pwv = PwR[(size_t)t * N + rc];     // per-lane, coalesced
        const double pw  = frozen ? 0.0 : pwv;
        #pragma unroll
        for (int c = 0; c < NB; ++c)
          r[c] -= pw * U12R[t * U12S + c];              // uniform -> s_load
      }
    }
    if (tid == k0f) {
      #pragma unroll
      for (int c = 0; c < NB; ++c) piv[0][c] = r[c];
      pinvs[0] = 1.0 / r[0];
    }
    __syncthreads();

    // 32 Jordan steps (round-6 verified structure, k0 = k0f)
    #pragma unroll
    for (int j = 0; j < NB; ++j) {
      const int pr = k0f + j;
      const int bsel = j & 1;
      if (tid < N && (tid < k0f || tid > pr)) {
        const double f = r[j] * pinvs[bsel];
        #pragma unroll
        for (int j2 = j + 1; j2 < NB; ++j2)
          r[j2] -= f * piv[bsel][j2];
        r[j] = f;
        if (j + 1 < NB && tid == pr + 1) {
          #pragma unroll
          for (int c = 0; c < NB; ++c)
            if (c > j) piv[bsel ^ 1][c] = r[c];
          pinvs[bsel ^ 1] = 1.0 / r[j + 1];
        }
      }
      __syncthreads();
    }

    // publish: band -> F11s + A; others -> Pw slot (p+1)&1
    if (tid < N) {
      if (tid >= k0f && tid < ctf) {
        const int fr = tid - k0f;
        #pragma unroll
        for (int c = 0; c < NB; ++c) {
          F11s[fr][c] = r[c];
          A[(size_t)tid * AP + k0f + c] = r[c];
        }
      } else {
        #pragma unroll
        for (int t = 0; t < NB; ++t)
          PwW[(size_t)t * N + tid] = r[t];
      }
    }
    __syncthreads();

    // U12 solve: raw band trailing + folded correction, then forward solve.
    // PwR[t*N + k0f + jr] is uniform (jr static, t loop) -> s_load.
    if (tid < tc2) {
      double u[NB];
      #pragma unroll
      for (int jr = 0; jr < NB; ++jr)
        u[jr] = A[(size_t)(k0f + jr) * AP + ctf + tid];
      #pragma unroll 2
      for (int t = 0; t < NB; ++t) {
        const double uv = U12R[t * U12S + NB + tid];    // per-lane, coalesced
        #pragma unroll
        for (int jr = 0; jr < NB; ++jr)
          u[jr] -= PwR[(size_t)t * N + k0f + jr] * uv;  // uniform -> s_load
      }
      #pragma unroll
      for (int jr = 1; jr < NB; ++jr) {
        double vv = u[jr];
        #pragma unroll
        for (int t = 0; t < jr; ++t)
          vv -= F11s[jr][t] * u[t];
        u[jr] = vv;
      }
      #pragma unroll
      for (int jr = 0; jr < NB; ++jr) {
        U12W[jr * U12S + tid] = u[jr];
        A[(size_t)(k0f + jr) * AP + ctf + tid] = u[jr];
      }
    }
    return;
  }

  // ---------- update(p): rows [0,k0u) U [ctf,N), cols [ctf,258) ----------
  const int nct = (tc2 + 63) / 64;
  const int t0  = bid - 1;
  if (t0 >= 7 * nct) return;
  const int rb0 = (t0 / nct) * 32;
  const int c0  = (t0 % nct) * 64;

  for (int i = tid; i < NB * 32; i += 512) {
    const int t = i >> 5, rr = i & 31;
    const int rb = rb0 + rr;
    const int gr = (rb < k0u) ? rb : rb + 2 * NB;       // skip bands p, p+1
    Pl[t][rr] = (rb < 193) ? PwR[(size_t)t * N + gr] : 0.0;
  }
  for (int i = tid; i < NB * 64; i += 512) {
    const int t = i >> 6, c = i & 63;
    Ul[t][c] = (c0 + c < tc2) ? U12R[t * U12S + NB + c0 + c] : 0.0;
  }
  __syncthreads();

  const int tr  = tid >> 4;          // 0..31 (row in tile)
  const int tcx = (tid & 15) * 4;    // col group
  const int rb  = rb0 + tr;
  const int gr  = (rb < k0u) ? rb : rb + 2 * NB;
  double acc[4];
  #pragma unroll
  for (int c = 0; c < 4; ++c)
    acc[c] = (rb < 193 && (c0 + tcx + c) < tc2)
           ? A[(size_t)gr * AP + ctf + c0 + tcx + c] : 0.0;
  #pragma unroll
  for (int t = 0; t < NB; ++t) {
    const double p0 = Pl[t][tr];
    const double2 u0 = *(const double2*)&Ul[t][tcx];
    const double2 u1 = *(const double2*)&Ul[t][tcx + 2];
    acc[0] -= p0 * u0.x; acc[1] -= p0 * u0.y;
    acc[2] -= p0 * u1.x; acc[3] -= p0 * u1.y;
  }
  #pragma unroll
  for (int c = 0; c < 4; ++c)
    if (rb < 193 && (c0 + tcx + c) < tc2)
      A[(size_t)gr * AP + ctf + c0 + tcx + c] = acc[c];
}

// ---------------------------------------------------------------------------
// last: update(p=7) (225 rows x 2 cols, rank-32) + finish back-substs.
// Reads Pw/U12 slot 1 (written by fused p=6's factor(7)).  [round-9 verified]
// ---------------------------------------------------------------------------
__global__ __launch_bounds__(256) void last_kernel(void* __restrict__ wsv) {
  __shared__ double xs[N];
  __shared__ double rr[256];
  double* A = (double*)((char*)wsv + A_BYTE);
  const double* Pw1  = (const double*)((const char*)wsv + PW_BYTE  + PWSZ);
  const double* U121 = (const double*)((const char*)wsv + U12_BYTE + U12SZ);
  float* w0f = (float*)((char*)wsv + W0_BYTE);
  const int tid = threadIdx.x;

  // update(7): rows [0,224) U {256}, cols {256, 257}
  for (int idx = tid; idx < 225 * 2; idx += 256) {
    const int rb = idx >> 1, c = idx & 1;
    const int gr = (rb < 224) ? rb : 256;
    double acc = A[(size_t)gr * AP + 256 + c];
    #pragma unroll
    for (int t = 0; t < NB; ++t)
      acc -= Pw1[(size_t)t * N + gr] * U121[t * U12S + c];
    A[(size_t)gr * AP + 256 + c] = acc;
  }
  __threadfence_block();
  __syncthreads();

  // finish (round-6 verified body)
  if (tid == 0) xs[256] = A[256 * AP + 257] / A[256 * AP + 256];
  __syncthreads();
  const double x256 = xs[256];
  rr[tid] = A[(size_t)tid * AP + 257] - A[(size_t)tid * AP + 256] * x256;
  __syncthreads();
  const int fk0 = tid & ~31;
  const int fs  = tid & 31;
  for (int j = 31; j >= 0; --j) {
    if (fs == j) xs[fk0 + j] = rr[fk0 + j] / A[(size_t)(fk0 + j) * AP + (fk0 + j)];
    __syncthreads();
    if (fs < j) rr[fk0 + fs] -= A[(size_t)(fk0 + fs) * AP + (fk0 + j)] * xs[fk0 + j];
    __syncthreads();
  }
  w0f[tid] = (float)xs[tid];
  if (tid == 0) w0f[256] = (float)xs[256];
}

// ---------------------------------------------------------------------------
// combine: out[(b,l), i] = sum_d St[d, i] * W[(b,l), d]   (round-4 version)
// ---------------------------------------------------------------------------
#define NL 8
__global__ __launch_bounds__(320) void combine_kernel(const float* __restrict__ S,
                                                      const float* __restrict__ om,
                                                      const void* __restrict__ wsv,
                                                      float* __restrict__ out) {
  const int tid = threadIdx.x;
  const int b  = blockIdx.y;
  const int l0 = blockIdx.x * NL;
  const float* w0  = (const float*)((const char*)wsv + W0_BYTE);
  const float* cxy = (const float*)((const char*)wsv + CXY_BYTE);
  const float* St  = (const float*)((const char*)wsv + ST_BYTE);
  __shared__ __align__(16) float Wl[N][NL];
  __shared__ float omsh[2 * MM];
  __shared__ float cxs[NL], cys[NL];

  for (int idx = tid; idx < 2 * MM; idx += 320) omsh[idx] = om[idx];
  if (tid < NL) {
    cxs[tid] = cxy[((size_t)(b * LL) + l0 + tid) * 2];
    cys[tid] = cxy[((size_t)(b * LL) + l0 + tid) * 2 + 1];
  }
  __syncthreads();

  for (int idx = tid; idx < NL * N; idx += 320) {
    const int d = idx >> 3;
    const int r = idx & 7;
    float v;
    if (d == 0) {
      v = w0[0];
    } else {
      const int m = (d - 1) >> 1;
      const int pq = 2 * m + 1;
      const float t = cxs[r] * omsh[2 * m] + cys[r] * omsh[2 * m + 1];
      float s, c;
      sincosf(t, &s, &c);
      const float a0 = w0[pq], a1 = w0[pq + 1];
      v = (d & 1) ? (c * a0 - s * a1) : (s * a0 + c * a1);
    }
    Wl[d][r] = v;
  }
  __syncthreads();

  const int i = tid;
  if (i < N) {
    float acc[NL];
    #pragma unroll
    for (int r = 0; r < NL; ++r) acc[r] = 0.0f;
    #pragma unroll 8
    for (int d = 0; d < N; ++d) {
      const float stv = St[(size_t)d * N + i];
      const float4 wa = *(const float4*)&Wl[d][0];
      const float4 wb = *(const float4*)&Wl[d][4];
      acc[0] += stv * wa.x; acc[1] += stv * wa.y;
      acc[2] += stv * wa.z; acc[3] += stv * wa.w;
      acc[4] += stv * wb.x; acc[5] += stv * wb.y;
      acc[6] += stv * wb.z; acc[7] += stv * wb.w;
    }
    const size_t base = (size_t)(b * LL + l0) * N + i;
    #pragma unroll
    for (int r = 0; r < NL; ++r) out[base + (size_t)r * N] = acc[r];
    if (l0 + NL == LL) {
      out[(size_t)BB * LL * N + (size_t)b * N + i] = acc[NL - 1];
    }
  }
}

extern "C" void kernel_launch(void* const* d_in, const int* in_sizes, int n_in,
                              void* d_out, int out_size, void* d_ws, size_t ws_size,
                              hipStream_t stream) {
  const float* x  = (const float*)d_in[0];   // (B, L, 2)
  const float* z0 = (const float*)d_in[1];   // (D,)
  const float* om = (const float*)d_in[2];   // (M, 2)
  const float* S  = (const float*)d_in[3];   // (D, D)
  float* out = (float*)d_out;                // outputs (B,L,D) then z_final (B,D)

  hipLaunchKernelGGL(stage_scan_kernel, dim3(131), dim3(512), 0, stream, S, z0, x, d_ws);
  hipLaunchKernelGGL(panel_factor_kernel, dim3(1), dim3(512), 0, stream, d_ws);
  for (int p = 0; p < 7; ++p)
    hipLaunchKernelGGL(update_factor_kernel, dim3(29), dim3(512), 0, stream, d_ws, p);
  hipLaunchKernelGGL(last_kernel, dim3(1), dim3(256), 0, stream, d_ws);
  hipLaunchKernelGGL(combine_kernel, dim3(LL / NL, BB), dim3(320), 0, stream, S, om, d_ws, out);
}

// Round 11
// 345.268 us; speedup vs baseline: 1.7195x; 1.7195x over previous
//
#include <hip/hip_runtime.h>
#include <math.h>

#define N    257     // state dim
#define AP   258     // doubles per A row (cols 0..256 = S, col 257 = rhs)
#define MM   128     // rotation pairs
#define LL   512     // seq length
#define BB   4       // batch
#define NB   32      // panel width
#define U12S 226     // U12 row stride

// ws byte layout (round-6 verified):
#define A_BYTE    0         // double[257*258] = 530448
#define W0_BYTE   530448    // float[257]  -> 531476
#define CXY_BYTE  531488    // float[4096] -> 547872
#define PW_BYTE   547904    // double[32*257] = 65792 -> 613696
#define U12_BYTE  613696    // double[32*226] = 57856 -> 671552
#define ST_BYTE   671552    // float[257*257] = 264196 -> 935748
// total ~936 KB (ws >= 1.31 MB)

// ---------------------------------------------------------------------------
// stage + scan in ONE dispatch (verified r9/r10): blocks 0..129 stage
// A=[S|z0] fp64 + St=S^T fp32; block 130 does the prefix-sum scan.
// ---------------------------------------------------------------------------
__global__ __launch_bounds__(512) void stage_scan_kernel(const float* __restrict__ S,
                                                         const float* __restrict__ z0,
                                                         const float* __restrict__ x,
                                                         void* __restrict__ wsv) {
  const int tid = threadIdx.x;
  const int bid = blockIdx.x;

  if (bid < 130) {
    double* A  = (double*)((char*)wsv + A_BYTE);
    float*  St = (float*)((char*)wsv + ST_BYTE);
    const int idx = bid * 512 + tid;
    if (idx < N * N) {
      const int i = idx / N, j = idx - i * N;
      A[(size_t)i * AP + j] = (double)S[idx];
      St[idx] = S[j * N + i];          // St[d][i] = S[i][d]
    } else if (idx < N * N + N) {
      const int r = idx - N * N;
      A[(size_t)r * AP + N] = (double)z0[r];
    }
    return;
  }

  const int wave = tid >> 6, lane = tid & 63;
  const int b    = wave >> 1, comp = wave & 1;
  const float* xp = x + ((size_t)b * LL) * 2 + comp;
  double loc[8];
  double run = 0.0;
  #pragma unroll
  for (int e = 0; e < 8; ++e) {
    run += (double)xp[(lane * 8 + e) * 2];
    loc[e] = run;
  }
  double tot = run;
  #pragma unroll
  for (int off = 1; off < 64; off <<= 1) {
    const double o = __shfl_up(tot, off);
    if (lane >= off) tot += o;
  }
  const double excl = tot - run;
  float* cp = (float*)((char*)wsv + CXY_BYTE) + ((size_t)b * LL) * 2 + comp;
  #pragma unroll
  for (int e = 0; e < 8; ++e)
    cp[(lane * 8 + e) * 2] = (float)(excl + loc[e]);
}

// ---------------------------------------------------------------------------
// panel factor: round-6 verified register-resident Jordan, now at 320
// threads (5 waves, covers N=257 rows and tc2<=226 cols).
// Why 320: per Jordan step every wave issues 31 broadcast ds_reads of the
// pivot row through the CU's ONE shared LDS pipe (~6cy each). 8 waves ->
// ~1.5k cy/step; only waves 0..4 do useful work (tid<257). 5 waves cuts
// pipe pressure 5/8 and shrinks every barrier.
// ---------------------------------------------------------------------------
__global__ __launch_bounds__(320, 1) void panel_factor_kernel(void* __restrict__ wsv,
                                                              int k0) {
  __shared__ double piv[2][NB];          // double-buffered pivot row trailing
  __shared__ double pinvs[2];
  __shared__ double F11s[NB][NB + 1];    // L11\U11 block (for U12 solve)
  double* A    = (double*)((char*)wsv + A_BYTE);
  double* Pw   = (double*)((char*)wsv + PW_BYTE);
  double* U12w = (double*)((char*)wsv + U12_BYTE);
  const int tid = threadIdx.x;
  const int ct  = k0 + NB;
  const int tc2 = 258 - ct;              // trailing cols incl rhs

  // ---- stage my row's panel slice into registers (L2-resident A) ----
  double r[NB];
  if (tid < N) {
    const double* Ar = A + (size_t)tid * AP + k0;   // 16B-aligned (k0,AP even)
    #pragma unroll
    for (int c = 0; c < NB; c += 2) {
      const double2 v = *(const double2*)&Ar[c];
      r[c] = v.x; r[c + 1] = v.y;
    }
  }

  // ---- pre-step: pivot row k0 publishes itself ----
  if (tid == k0) {
    #pragma unroll
    for (int c = 0; c < NB; ++c) piv[0][c] = r[c];
    pinvs[0] = 1.0 / r[0];
  }
  __syncthreads();

  // ---- 32 Jordan steps, rows in registers, pivot row via LDS broadcast ----
  #pragma unroll
  for (int j = 0; j < NB; ++j) {
    const int pr = k0 + j;
    const int bsel = j & 1;
    if (tid < N && (tid < k0 || tid > pr)) {   // frozen: pivot rows k0..pr
      const double f = r[j] * pinvs[bsel];
      #pragma unroll
      for (int j2 = j + 1; j2 < NB; ++j2)
        r[j2] -= f * piv[bsel][j2];
      r[j] = f;
      if (j + 1 < NB && tid == pr + 1) {       // publish next pivot row
        #pragma unroll
        for (int c = 0; c < NB; ++c)
          if (c > j) piv[bsel ^ 1][c] = r[c];
        pinvs[bsel ^ 1] = 1.0 / r[j + 1];
      }
    }
    __syncthreads();
  }

  // ---- publish: pivot band -> F11s + A; other rows -> Pw ----
  if (tid < N) {
    if (tid >= k0 && tid < ct) {
      const int fr = tid - k0;
      #pragma unroll
      for (int c = 0; c < NB; ++c) {
        F11s[fr][c] = r[c];
        A[(size_t)tid * AP + k0 + c] = r[c];   // U11/L11 for finish kernel
      }
    } else {
      #pragma unroll
      for (int t = 0; t < NB; ++t)
        Pw[(size_t)t * N + tid] = r[t];
    }
  }
  __syncthreads();                             // F11s ready

  // ---- U12 forward solve: thread owns column, u[] in registers ----
  if (tid < tc2) {
    double u[NB];
    #pragma unroll
    for (int jr = 0; jr < NB; ++jr)
      u[jr] = A[(size_t)(k0 + jr) * AP + ct + tid];   // coalesced across tid
    #pragma unroll
    for (int jr = 1; jr < NB; ++jr) {
      double vv = u[jr];
      #pragma unroll
      for (int t = 0; t < jr; ++t)
        vv -= F11s[jr][t] * u[t];              // F11 broadcast, u in regs
      u[jr] = vv;
    }
    #pragma unroll
    for (int jr = 0; jr < NB; ++jr) {
      U12w[jr * U12S + tid] = u[jr];
      A[(size_t)(k0 + jr) * AP + ct + tid] = u[jr];
    }
  }
}

// ---------------------------------------------------------------------------
// panel update (rank-32 Jordan GEMM), round-6 verified body (p = 0..6):
//   rows R = [0,k0) U [ct,N)  (225 rows; gr = rb<k0 ? rb : rb+32)
//   cols [ct, 258): A[gr][c] -= sum_t Pw[t][gr] * U12[t][c-ct]
// block tile = 32 rows x 64 cols; thread tile = 2x4.
// ---------------------------------------------------------------------------
__global__ __launch_bounds__(256) void panel_update_kernel(void* __restrict__ wsv,
                                                           int k0, int tc2) {
  __shared__ double Pl[NB][NB + 1];
  __shared__ __align__(16) double Ul[NB][66];
  double* A = (double*)((char*)wsv + A_BYTE);
  const double* Pw   = (const double*)((const char*)wsv + PW_BYTE);
  const double* U12w = (const double*)((const char*)wsv + U12_BYTE);
  const int tid = threadIdx.x;
  const int ct  = k0 + NB;
  const int rb0 = blockIdx.x * 32;
  const int c0  = blockIdx.y * 64;

  for (int i = tid; i < 32 * 32; i += 256) {
    const int t = i >> 5, rr = i & 31;
    const int rb = rb0 + rr;
    const int gr = (rb < k0) ? rb : rb + NB;
    Pl[t][rr] = (rb < 225) ? Pw[(size_t)t * N + gr] : 0.0;
  }
  for (int i = tid; i < 32 * 64; i += 256) {
    const int t = i >> 6, c = i & 63;
    Ul[t][c] = (c0 + c < tc2) ? U12w[t * U12S + c0 + c] : 0.0;
  }
  __syncthreads();

  const int tr  = tid >> 4;          // 0..15 -> rows tr*2 .. +1
  const int tcx = (tid & 15) * 4;    // cols tcx .. +3
  double acc[2][4];
  #pragma unroll
  for (int rr = 0; rr < 2; ++rr) {
    const int rb = rb0 + tr * 2 + rr;
    const int gr = (rb < k0) ? rb : rb + NB;
    #pragma unroll
    for (int c = 0; c < 4; ++c)
      acc[rr][c] = (rb < 225 && (c0 + tcx + c) < tc2)
                 ? A[(size_t)gr * AP + ct + c0 + tcx + c] : 0.0;
  }
  #pragma unroll
  for (int t = 0; t < NB; ++t) {
    const double p0 = Pl[t][tr * 2], p1 = Pl[t][tr * 2 + 1];
    const double2 u0 = *(const double2*)&Ul[t][tcx];
    const double2 u1 = *(const double2*)&Ul[t][tcx + 2];
    acc[0][0] -= p0 * u0.x; acc[0][1] -= p0 * u0.y;
    acc[0][2] -= p0 * u1.x; acc[0][3] -= p0 * u1.y;
    acc[1][0] -= p1 * u0.x; acc[1][1] -= p1 * u0.y;
    acc[1][2] -= p1 * u1.x; acc[1][3] -= p1 * u1.y;
  }
  #pragma unroll
  for (int rr = 0; rr < 2; ++rr) {
    const int rb = rb0 + tr * 2 + rr;
    const int gr = (rb < k0) ? rb : rb + NB;
    #pragma unroll
    for (int c = 0; c < 4; ++c)
      if (rb < 225 && (c0 + tcx + c) < tc2)
        A[(size_t)gr * AP + ct + c0 + tcx + c] = acc[rr][c];
  }
}

// ---------------------------------------------------------------------------
// last: update(p=7) (225 rows x 2 cols, rank-32) + finish back-substs
// (verified r9/r10 body, re-pointed at the single Pw/U12 buffers).
// ---------------------------------------------------------------------------
__global__ __launch_bounds__(256) void last_kernel(void* __restrict__ wsv) {
  __shared__ double xs[N];
  __shared__ double rr[256];
  double* A = (double*)((char*)wsv + A_BYTE);
  const double* Pw   = (const double*)((const char*)wsv + PW_BYTE);
  const double* U12w = (const double*)((const char*)wsv + U12_BYTE);
  float* w0f = (float*)((char*)wsv + W0_BYTE);
  const int tid = threadIdx.x;

  // update(7): rows [0,224) U {256}, cols {256, 257}
  for (int idx = tid; idx < 225 * 2; idx += 256) {
    const int rb = idx >> 1, c = idx & 1;
    const int gr = (rb < 224) ? rb : 256;
    double acc = A[(size_t)gr * AP + 256 + c];
    #pragma unroll
    for (int t = 0; t < NB; ++t)
      acc -= Pw[(size_t)t * N + gr] * U12w[t * U12S + c];
    A[(size_t)gr * AP + 256 + c] = acc;
  }
  __threadfence_block();
  __syncthreads();

  // finish (round-6 verified body)
  if (tid == 0) xs[256] = A[256 * AP + 257] / A[256 * AP + 256];
  __syncthreads();
  const double x256 = xs[256];
  rr[tid] = A[(size_t)tid * AP + 257] - A[(size_t)tid * AP + 256] * x256;
  __syncthreads();
  const int fk0 = tid & ~31;
  const int fs  = tid & 31;
  for (int j = 31; j >= 0; --j) {
    if (fs == j) xs[fk0 + j] = rr[fk0 + j] / A[(size_t)(fk0 + j) * AP + (fk0 + j)];
    __syncthreads();
    if (fs < j) rr[fk0 + fs] -= A[(size_t)(fk0 + fs) * AP + (fk0 + j)] * xs[fk0 + j];
    __syncthreads();
  }
  w0f[tid] = (float)xs[tid];
  if (tid == 0) w0f[256] = (float)xs[256];
}

// ---------------------------------------------------------------------------
// combine: out[(b,l), i] = sum_d St[d, i] * W[(b,l), d]   (round-4 verified)
// ---------------------------------------------------------------------------
#define NL 8
__global__ __launch_bounds__(320) void combine_kernel(const float* __restrict__ S,
                                                      const float* __restrict__ om,
                                                      const void* __restrict__ wsv,
                                                      float* __restrict__ out) {
  const int tid = threadIdx.x;
  const int b  = blockIdx.y;
  const int l0 = blockIdx.x * NL;
  const float* w0  = (const float*)((const char*)wsv + W0_BYTE);
  const float* cxy = (const float*)((const char*)wsv + CXY_BYTE);
  const float* St  = (const float*)((const char*)wsv + ST_BYTE);
  __shared__ __align__(16) float Wl[N][NL];
  __shared__ float omsh[2 * MM];
  __shared__ float cxs[NL], cys[NL];

  for (int idx = tid; idx < 2 * MM; idx += 320) omsh[idx] = om[idx];
  if (tid < NL) {
    cxs[tid] = cxy[((size_t)(b * LL) + l0 + tid) * 2];
    cys[tid] = cxy[((size_t)(b * LL) + l0 + tid) * 2 + 1];
  }
  __syncthreads();

  for (int idx = tid; idx < NL * N; idx += 320) {
    const int d = idx >> 3;
    const int r = idx & 7;
    float v;
    if (d == 0) {
      v = w0[0];
    } else {
      const int m = (d - 1) >> 1;
      const int pq = 2 * m + 1;
      const float t = cxs[r] * omsh[2 * m] + cys[r] * omsh[2 * m + 1];
      float s, c;
      sincosf(t, &s, &c);
      const float a0 = w0[pq], a1 = w0[pq + 1];
      v = (d & 1) ? (c * a0 - s * a1) : (s * a0 + c * a1);
    }
    Wl[d][r] = v;
  }
  __syncthreads();

  const int i = tid;
  if (i < N) {
    float acc[NL];
    #pragma unroll
    for (int r = 0; r < NL; ++r) acc[r] = 0.0f;
    #pragma unroll 8
    for (int d = 0; d < N; ++d) {
      const float stv = St[(size_t)d * N + i];
      const float4 wa = *(const float4*)&Wl[d][0];
      const float4 wb = *(const float4*)&Wl[d][4];
      acc[0] += stv * wa.x; acc[1] += stv * wa.y;
      acc[2] += stv * wa.z; acc[3] += stv * wa.w;
      acc[4] += stv * wb.x; acc[5] += stv * wb.y;
      acc[6] += stv * wb.z; acc[7] += stv * wb.w;
    }
    const size_t base = (size_t)(b * LL + l0) * N + i;
    #pragma unroll
    for (int r = 0; r < NL; ++r) out[base + (size_t)r * N] = acc[r];
    if (l0 + NL == LL) {
      out[(size_t)BB * LL * N + (size_t)b * N + i] = acc[NL - 1];
    }
  }
}

extern "C" void kernel_launch(void* const* d_in, const int* in_sizes, int n_in,
                              void* d_out, int out_size, void* d_ws, size_t ws_size,
                              hipStream_t stream) {
  const float* x  = (const float*)d_in[0];   // (B, L, 2)
  const float* z0 = (const float*)d_in[1];   // (D,)
  const float* om = (const float*)d_in[2];   // (M, 2)
  const float* S  = (const float*)d_in[3];   // (D, D)
  float* out = (float*)d_out;                // outputs (B,L,D) then z_final (B,D)

  hipLaunchKernelGGL(stage_scan_kernel, dim3(131), dim3(512), 0, stream, S, z0, x, d_ws);
  for (int p = 0; p < 8; ++p) {
    const int k0  = p * NB;
    const int tc2 = 258 - (k0 + NB);
    hipLaunchKernelGGL(panel_factor_kernel, dim3(1), dim3(320), 0, stream, d_ws, k0);
    if (p < 7)
      hipLaunchKernelGGL(panel_update_kernel, dim3(8, (tc2 + 63) / 64), dim3(256),
                         0, stream, d_ws, k0, tc2);
  }
  hipLaunchKernelGGL(last_kernel, dim3(1), dim3(256), 0, stream, d_ws);
  hipLaunchKernelGGL(combine_kernel, dim3(LL / NL, BB), dim3(320), 0, stream, S, om, d_ws, out);
}